// Round 2
// baseline (282.600 us; speedup 1.0000x reference)
//
#include <hip/hip_runtime.h>
#include <hip/hip_bf16.h>

typedef __attribute__((ext_vector_type(8))) short short8;
typedef __attribute__((ext_vector_type(4))) float f32x4;

__device__ __forceinline__ ushort f2bf(float x) {
    __hip_bfloat16 h = __float2bfloat16(x);
    union { __hip_bfloat16 hh; ushort u; } cv;
    cv.hh = h;
    return cv.u;
}

// ---------------------------------------------------------------------------
// Kernel 1: prep — bf16-cast a/b, compute feature maps fa/fb (fp32 -> bf16),
// and fp32 row squared-norms. Packed layout: [row][96] = [a(64) | fa(32)].
// 16 rows per 256-thread block; W1/W2 staged in LDS (padded, conflict-free).
// ---------------------------------------------------------------------------
__global__ __launch_bounds__(256) void prep_kernel(
    const float* __restrict__ a, const float* __restrict__ b,
    const float* __restrict__ W1, const float* __restrict__ b1v,
    const float* __restrict__ W2, const float* __restrict__ b2v,
    ushort* __restrict__ af, ushort* __restrict__ bfp,
    float* __restrict__ asq, float* __restrict__ bsq)
{
    __shared__ float sW1[32][65];   // pad 65: stride%32==1 -> conflict-free
    __shared__ float sW2[32][33];
    __shared__ float sB1[32];
    __shared__ float sB2[32];
    __shared__ float sX[16][64];
    __shared__ float sH[16][33];

    const int t = threadIdx.x;
    for (int i = t; i < 32 * 64; i += 256) sW1[i >> 6][i & 63] = W1[i];
    for (int i = t; i < 32 * 32; i += 256) sW2[i >> 5][i & 31] = W2[i];
    if (t < 32) { sB1[t] = b1v[t]; sB2[t] = b2v[t]; }

    const int rowBase = blockIdx.x * 16;   // 0..16383, blocks never straddle a/b
    const float* src; ushort* dstf; float* dsq; int row0;
    if (rowBase < 8192) { src = a; dstf = af;  dsq = asq; row0 = rowBase; }
    else                { src = b; dstf = bfp; dsq = bsq; row0 = rowBase - 8192; }

    for (int i = t; i < 16 * 64; i += 256) {
        int r = i >> 6, k = i & 63;
        float x = src[(size_t)(row0 + r) * 64 + k];
        sX[r][k] = x;
        dstf[(size_t)(row0 + r) * 96 + k] = f2bf(x);
    }
    __syncthreads();

    // layer 1: h = tanh(x @ W1^T + b1)   (16 rows x 32 hid = 512 dots)
    for (int i = t; i < 16 * 32; i += 256) {
        int r = i >> 5, j = i & 31;
        float acc = sB1[j];
        #pragma unroll
        for (int k = 0; k < 64; ++k) acc += sX[r][k] * sW1[j][k];
        sH[r][j] = tanhf(acc);
    }
    __syncthreads();

    // layer 2: f = h @ W2^T + b2 -> bf16
    for (int i = t; i < 16 * 32; i += 256) {
        int r = i >> 5, j = i & 31;
        float acc = sB2[j];
        #pragma unroll
        for (int k = 0; k < 32; ++k) acc += sH[r][k] * sW2[j][k];
        dstf[(size_t)(row0 + r) * 96 + 64 + j] = f2bf(acc);
    }

    // fp32 squared norms (exact)
    if (t < 16) {
        float s = 0.f;
        #pragma unroll
        for (int k = 0; k < 64; ++k) s += sX[t][k] * sX[t][k];
        dsq[row0 + t] = s;
    }
}

// ---------------------------------------------------------------------------
// Kernel 2: fused dual-Gram. 128x128 output tile per 256-thread block
// (4 waves = 2x2 of 64x64). Whole K (96) staged once -> no K loop.
// MFMA 16x16x32 bf16; two accumulator sets (rbf-dot over k=0..63,
// q-dot over k=64..95). Epilogue: exp + blend, fp32 streaming store.
// ---------------------------------------------------------------------------
#define LDP 104   // padded LDS row width in bf16 units (52 dwords -> 2-way max)

__global__ __launch_bounds__(256) void gram_kernel(
    const ushort* __restrict__ af, const ushort* __restrict__ bfp,
    const float* __restrict__ asq, const float* __restrict__ bsq,
    float* __restrict__ out)
{
    __shared__ ushort sA[128 * LDP];
    __shared__ ushort sB[128 * LDP];
    __shared__ float sAsq[128];
    __shared__ float sBsq[128];

    const int t = threadIdx.x;
    const int rowBase = blockIdx.y << 7;
    const int colBase = blockIdx.x << 7;

    // stage: 2 threads per row, 96B (6 x 16B) each, coalesced
    {
        const int r = t >> 1, half = t & 1;
        const uint4* srcA = (const uint4*)(af  + (size_t)(rowBase + r) * 96 + half * 48);
        const uint4* srcB = (const uint4*)(bfp + (size_t)(colBase + r) * 96 + half * 48);
        uint4* dA = (uint4*)(sA + r * LDP + half * 48);
        uint4* dB = (uint4*)(sB + r * LDP + half * 48);
        #pragma unroll
        for (int c = 0; c < 6; ++c) { dA[c] = srcA[c]; dB[c] = srcB[c]; }
    }
    if (t < 128) sAsq[t] = asq[rowBase + t];
    else         sBsq[t - 128] = bsq[colBase + (t - 128)];
    __syncthreads();

    const int lane = t & 63;
    const int w  = t >> 6;
    const int wr = w >> 1, wc = w & 1;
    const int lr = lane & 15, lk = lane >> 4;

    // A fragments: lane holds A[row=lr][k = ks*32 + lk*8 .. +8)
    short8 aF[4][3];
    #pragma unroll
    for (int m = 0; m < 4; ++m)
        #pragma unroll
        for (int ks = 0; ks < 3; ++ks)
            aF[m][ks] = *(const short8*)(sA + (wr * 64 + m * 16 + lr) * LDP + ks * 32 + lk * 8);

    f32x4 accd[4][4], accq[4][4];
    #pragma unroll
    for (int m = 0; m < 4; ++m)
        #pragma unroll
        for (int n = 0; n < 4; ++n) {
            accd[m][n] = (f32x4){0.f, 0.f, 0.f, 0.f};
            accq[m][n] = (f32x4){0.f, 0.f, 0.f, 0.f};
        }

    #pragma unroll
    for (int n = 0; n < 4; ++n) {
        const int cb = (wc * 64 + n * 16 + lr) * LDP + lk * 8;
        short8 b0 = *(const short8*)(sB + cb);
        short8 b1 = *(const short8*)(sB + cb + 32);
        short8 b2 = *(const short8*)(sB + cb + 64);
        #pragma unroll
        for (int m = 0; m < 4; ++m) {
            accd[m][n] = __builtin_amdgcn_mfma_f32_16x16x32_bf16(aF[m][0], b0, accd[m][n], 0, 0, 0);
            accd[m][n] = __builtin_amdgcn_mfma_f32_16x16x32_bf16(aF[m][1], b1, accd[m][n], 0, 0, 0);
            accq[m][n] = __builtin_amdgcn_mfma_f32_16x16x32_bf16(aF[m][2], b2, accq[m][n], 0, 0, 0);
        }
    }

    // epilogue: C/D layout col=lane&15, row=(lane>>4)*4+reg  [m89/m91]
    #pragma unroll
    for (int m = 0; m < 4; ++m) {
        #pragma unroll
        for (int n = 0; n < 4; ++n) {
            const int col = wc * 64 + n * 16 + lr;
            const float bsqv = sBsq[col];
            #pragma unroll
            for (int j = 0; j < 4; ++j) {
                const int row = wr * 64 + m * 16 + lk * 4 + j;
                const float d = accd[m][n][j];
                const float q = accq[m][n][j];
                const float sq = sAsq[row] + bsqv - 2.0f * d;
                const float rbf = __expf(-fmaxf(sq, 0.0f));
                out[(size_t)(rowBase + row) * 8192 + (colBase + col)] = 0.5f * q + 0.5f * rbf;
            }
        }
    }
}

// ---------------------------------------------------------------------------
extern "C" void kernel_launch(void* const* d_in, const int* in_sizes, int n_in,
                              void* d_out, int out_size, void* d_ws, size_t ws_size,
                              hipStream_t stream)
{
    const float* a  = (const float*)d_in[0];
    const float* b  = (const float*)d_in[1];
    const float* W1 = (const float*)d_in[2];
    const float* b1 = (const float*)d_in[3];
    const float* W2 = (const float*)d_in[4];
    const float* b2 = (const float*)d_in[5];
    float* out = (float*)d_out;

    char* ws = (char*)d_ws;
    ushort* af  = (ushort*)(ws);                              // 8192*96 bf16
    ushort* bfp = (ushort*)(ws + (size_t)8192 * 96 * 2);      // 8192*96 bf16
    float*  asq = (float*)(ws + (size_t)2 * 8192 * 96 * 2);
    float*  bsq = (float*)(ws + (size_t)2 * 8192 * 96 * 2 + 8192 * 4);

    prep_kernel<<<1024, 256, 0, stream>>>(a, b, W1, b1, W2, b2, af, bfp, asq, bsq);
    gram_kernel<<<dim3(64, 64), 256, 0, stream>>>(af, bfp, asq, bsq, out);
}